// Round 1
// baseline (853.540 us; speedup 1.0000x reference)
//
#include <hip/hip_runtime.h>
#include <stdint.h>

#define N_ATOMS 500000
#define N_MOLS  25000
#define HID     300
#define BA      64        // atoms per block
#define LROW    328       // Hs row stride (bf16 elems), padded for bank spread
#define WS_ELE  102400    // elements per repacked W matrix (10*2*10*64*8)

typedef __attribute__((ext_vector_type(8)))  short          short8v;
typedef __attribute__((ext_vector_type(8)))  unsigned short ushort8v;
typedef __attribute__((ext_vector_type(16))) float          f32x16;

static __device__ __forceinline__ unsigned short f2bf(float f) {
  unsigned int u = __float_as_uint(f);
  u += 0x7fffu + ((u >> 16) & 1u);   // round-to-nearest-even
  return (unsigned short)(u >> 16);
}

// ---------------------------------------------------------------------------
// Prep: repack W1/V1 into B-fragment order [kc:10][ks:2][nt:10][lane:64][j:8],
// pad biases/readout vectors to 320, zero the segment-sum accumulators.
// ---------------------------------------------------------------------------
__global__ void prep_kernel(
    const float* __restrict__ W1, const float* __restrict__ V1,
    const float* __restrict__ b1, const float* __restrict__ vb1,
    const float* __restrict__ W2, const float* __restrict__ V2,
    unsigned short* __restrict__ W1s, unsigned short* __restrict__ V1s,
    float* __restrict__ b1p, float* __restrict__ vb1p,
    float* __restrict__ W2p, float* __restrict__ V2p,
    float* __restrict__ sums)
{
  const int t = blockIdx.x * 256 + threadIdx.x;
  if (t < 2 * WS_ELE) {
    const float* src = (t < WS_ELE) ? W1 : V1;
    unsigned short* dst = (t < WS_ELE) ? W1s : V1s;
    const int i    = (t < WS_ELE) ? t : t - WS_ELE;
    const int j    = i & 7;
    const int lane = (i >> 3) & 63;
    const int nt   = (i >> 9) % 10;
    const int ks   = (i / 5120) & 1;
    const int kc   = i / 10240;
    const int k = kc * 32 + ks * 16 + (lane >> 5) * 8 + j;
    const int n = nt * 32 + (lane & 31);
    const float v = (k < HID && n < HID) ? src[k * HID + n] : 0.f;
    dst[i] = f2bf(v);
  } else if (t < 2 * WS_ELE + 1280) {
    const int i = t - 2 * WS_ELE;
    const int which = i / 320;
    const int e = i - which * 320;
    const float* s = (which == 0) ? b1 : (which == 1) ? vb1 : (which == 2) ? W2 : V2;
    float*       d = (which == 0) ? b1p : (which == 1) ? vb1p : (which == 2) ? W2p : V2p;
    d[e] = (e < HID) ? s[e] : 0.f;
  } else if (t < 2 * WS_ELE + 1280 + 2 * N_MOLS) {
    sums[t - (2 * WS_ELE + 1280)] = 0.f;
  }
}

// ---------------------------------------------------------------------------
// Fused FFN x2: per block of 64 atoms, stage H (bf16) once, run two GEMM
// passes (W1 then V1) with fused relu->dot(W2)->reduce epilogue.
// Wave layout: 4 waves = 2 (atom halves, 32 rows) x 2 (col halves, 160 cols).
// MFMA v_mfma_f32_32x32x16_bf16; acc 5 tiles x f32x16 per wave.
// ---------------------------------------------------------------------------
__global__ __launch_bounds__(256, 2) void fused_ffn(
    const float* __restrict__ hidden,
    const unsigned short* __restrict__ W1s, const unsigned short* __restrict__ V1s,
    const float* __restrict__ b1p, const float* __restrict__ vb1p,
    const float* __restrict__ W2p, const float* __restrict__ V2p,
    const float* __restrict__ b2, const float* __restrict__ vb2,
    float* __restrict__ outA, float* __restrict__ outW)
{
  __shared__ unsigned short Hs[BA][LROW];       // 41,984 B
  __shared__ unsigned short Bs[2][10][64][8];   // 20,480 B (one K-chunk of W)
  __shared__ float sOut[BA];

  const int tid = (int)threadIdx.x;
  const int ln  = tid & 63;
  const int wv  = tid >> 6;
  const int wm  = wv >> 1;      // atom half (0..1)
  const int wn  = wv & 1;       // col half (0..1)
  const int l31 = ln & 31;
  const int lh  = ln >> 5;
  const long base = (long)blockIdx.x * BA;

  // ---- stage H: f32 -> bf16 into LDS, zero-pad cols [300,328) + OOB rows ----
  for (int idx = tid; idx < BA * (LROW / 4); idx += 256) {
    const int row = idx / (LROW / 4);
    const int q   = idx - row * (LROW / 4);
    unsigned short v0 = 0, v1 = 0, v2 = 0, v3 = 0;
    const long atom = base + row;
    if (q < 75 && atom < N_ATOMS) {
      const float4 f = *reinterpret_cast<const float4*>(hidden + atom * HID + q * 4);
      v0 = f2bf(f.x); v1 = f2bf(f.y); v2 = f2bf(f.z); v3 = f2bf(f.w);
    }
    ushort4* p = reinterpret_cast<ushort4*>(&Hs[row][q * 4]);
    *p = make_ushort4(v0, v1, v2, v3);
  }
  __syncthreads();

  const unsigned short* bsf_src;
  unsigned short* const bsf = &Bs[0][0][0][0];

  for (int p = 0; p < 2; ++p) {
    const unsigned short* Ws = p ? V1s : W1s;
    const float* bb  = p ? vb1p : b1p;
    const float* w2  = p ? V2p  : W2p;
    float*       dst = p ? outW : outA;
    const float bias2 = p ? vb2[0] : b2[0];

    f32x16 acc[5] = {};   // zero-init accumulators

    for (int kc = 0; kc < 10; ++kc) {
      __syncthreads();  // previous chunk fully consumed (or H-stage / prev pass done)
      // stage 20KB of frag-ordered W into LDS (contiguous b128 copies)
      bsf_src = Ws + kc * 10240;
      for (int i = tid; i < 1280; i += 256) {
        reinterpret_cast<ushort8v*>(bsf)[i] =
            reinterpret_cast<const ushort8v*>(bsf_src)[i];
      }
      __syncthreads();

      #pragma unroll
      for (int ks = 0; ks < 2; ++ks) {
        const short8v a = *reinterpret_cast<const short8v*>(
            &Hs[wm * 32 + l31][kc * 32 + ks * 16 + lh * 8]);
        #pragma unroll
        for (int nt = 0; nt < 5; ++nt) {
          const short8v b = *reinterpret_cast<const short8v*>(
              &Bs[ks][wn * 5 + nt][ln][0]);
          acc[nt] = __builtin_amdgcn_mfma_f32_32x32x16_bf16(a, b, acc[nt], 0, 0, 0);
        }
      }
    }

    // ---- epilogue: out[atom] = sum_n relu(X+b1)*W2 + b2 ----
    float bv[5], w2v[5];
    #pragma unroll
    for (int nt = 0; nt < 5; ++nt) {
      const int c = wn * 160 + nt * 32 + l31;
      bv[nt]  = bb[c];
      w2v[nt] = w2[c];
    }
    __syncthreads();
    if (tid < BA) sOut[tid] = 0.f;
    __syncthreads();

    #pragma unroll
    for (int r = 0; r < 16; ++r) {
      float s = 0.f;
      #pragma unroll
      for (int nt = 0; nt < 5; ++nt) {
        float x = acc[nt][r] + bv[nt];
        x = fmaxf(x, 0.f);
        s = fmaf(x, w2v[nt], s);
      }
      // reduce across the 32 lanes of this half (cols); stays within half
      s += __shfl_xor(s, 1);
      s += __shfl_xor(s, 2);
      s += __shfl_xor(s, 4);
      s += __shfl_xor(s, 8);
      s += __shfl_xor(s, 16);
      if (l31 == 0) {
        const int row = (r & 3) + 8 * (r >> 2) + 4 * lh;
        atomicAdd(&sOut[wm * 32 + row], s);
      }
    }
    __syncthreads();
    if (tid < BA) {
      const long atom = base + tid;
      if (atom < N_ATOMS) dst[atom] = sOut[tid] + bias2;
    }
  }
}

// ---------------------------------------------------------------------------
// Segment sums: sorted seg_ids, each thread handles 8 atoms and run-compresses
// before hitting global atomics. 500000 = 8 * 62500 exactly.
// ---------------------------------------------------------------------------
__global__ void segsum_kernel(
    const float* __restrict__ outA, const float* __restrict__ outW,
    const int* __restrict__ seg,
    float* __restrict__ sum_o, float* __restrict__ sum_w)
{
  const long i0 = ((long)blockIdx.x * 256 + threadIdx.x) * 8;
  if (i0 >= N_ATOMS) return;
  const int4   s0 = *reinterpret_cast<const int4*>(seg + i0);
  const int4   s1 = *reinterpret_cast<const int4*>(seg + i0 + 4);
  const float4 o0 = *reinterpret_cast<const float4*>(outA + i0);
  const float4 o1 = *reinterpret_cast<const float4*>(outA + i0 + 4);
  const float4 w0 = *reinterpret_cast<const float4*>(outW + i0);
  const float4 w1 = *reinterpret_cast<const float4*>(outW + i0 + 4);
  const int   ss[8] = {s0.x, s0.y, s0.z, s0.w, s1.x, s1.y, s1.z, s1.w};
  const float oo[8] = {o0.x, o0.y, o0.z, o0.w, o1.x, o1.y, o1.z, o1.w};
  const float ww[8] = {w0.x, w0.y, w0.z, w0.w, w1.x, w1.y, w1.z, w1.w};
  int cur = ss[0];
  float ao = 0.f, aw = 0.f;
  #pragma unroll
  for (int j = 0; j < 8; ++j) {
    if (ss[j] != cur) {
      atomicAdd(&sum_o[cur], ao);
      atomicAdd(&sum_w[cur], aw);
      cur = ss[j]; ao = 0.f; aw = 0.f;
    }
    ao += oo[j]; aw += ww[j];
  }
  atomicAdd(&sum_o[cur], ao);
  atomicAdd(&sum_w[cur], aw);
}

// ---------------------------------------------------------------------------
// Final: out = output + weights * (0 - sum_o[seg]) / sum_w'[seg]
// ---------------------------------------------------------------------------
__global__ void final_kernel(
    const float* __restrict__ outA, const float* __restrict__ outW,
    const int* __restrict__ seg,
    const float* __restrict__ sum_o, const float* __restrict__ sum_w,
    float* __restrict__ out)
{
  const long i0 = ((long)blockIdx.x * 256 + threadIdx.x) * 4;
  if (i0 >= N_ATOMS) return;
  const int4   s4 = *reinterpret_cast<const int4*>(seg + i0);
  const float4 o4 = *reinterpret_cast<const float4*>(outA + i0);
  const float4 w4 = *reinterpret_cast<const float4*>(outW + i0);
  const int   ss[4] = {s4.x, s4.y, s4.z, s4.w};
  const float oo[4] = {o4.x, o4.y, o4.z, o4.w};
  const float ww[4] = {w4.x, w4.y, w4.z, w4.w};
  float r[4];
  #pragma unroll
  for (int j = 0; j < 4; ++j) {
    const int s = ss[j];
    float sw = sum_w[s];
    sw = (sw == 0.f) ? 1.f : sw;
    const float corr = (0.f - sum_o[s]) / sw;
    r[j] = oo[j] + ww[j] * corr;
  }
  *reinterpret_cast<float4*>(out + i0) = make_float4(r[0], r[1], r[2], r[3]);
}

// ---------------------------------------------------------------------------
extern "C" void kernel_launch(void* const* d_in, const int* in_sizes, int n_in,
                              void* d_out, int out_size, void* d_ws, size_t ws_size,
                              hipStream_t stream)
{
  const float* hidden = (const float*)d_in[0];
  const int*   seg    = (const int*)d_in[1];
  const float* W1     = (const float*)d_in[2];
  const float* b1     = (const float*)d_in[3];
  const float* W2     = (const float*)d_in[4];
  const float* b2     = (const float*)d_in[5];
  const float* V1     = (const float*)d_in[6];
  const float* vb1    = (const float*)d_in[7];
  const float* V2     = (const float*)d_in[8];
  const float* vb2    = (const float*)d_in[9];

  char* ws = (char*)d_ws;
  float*          outA  = (float*)(ws + 0);          // 2,000,000 B
  float*          outW  = (float*)(ws + 2000000);    // 2,000,000 B
  float*          sum_o = (float*)(ws + 4000000);    //   100,000 B
  float*          sum_w = (float*)(ws + 4100000);    //   100,000 B
  unsigned short* W1s   = (unsigned short*)(ws + 4200000);  // 204,800 B
  unsigned short* V1s   = (unsigned short*)(ws + 4404800);  // 204,800 B
  float*          b1p   = (float*)(ws + 4609600);    // 1,280 B
  float*          vb1p  = (float*)(ws + 4610880);
  float*          W2p   = (float*)(ws + 4612160);
  float*          V2p   = (float*)(ws + 4613440);

  prep_kernel<<<1001, 256, 0, stream>>>(W1, V1, b1, vb1, W2, V2,
                                        W1s, V1s, b1p, vb1p, W2p, V2p, sum_o);

  const int nblk = (N_ATOMS + BA - 1) / BA;   // 7813
  fused_ffn<<<nblk, 256, 0, stream>>>(hidden, W1s, V1s, b1p, vb1p, W2p, V2p,
                                      b2, vb2, outA, outW);

  segsum_kernel<<<(N_ATOMS / 8 + 255) / 256, 256, 0, stream>>>(outA, outW, seg,
                                                               sum_o, sum_w);

  final_kernel<<<(N_ATOMS / 4 + 255) / 256, 256, 0, stream>>>(outA, outW, seg,
                                                              sum_o, sum_w,
                                                              (float*)d_out);
}

// Round 2
// 418.712 us; speedup vs baseline: 2.0385x; 2.0385x over previous
//
#include <hip/hip_runtime.h>
#include <stdint.h>

#define N_ATOMS 500000
#define N_MOLS  25000
#define HID     300
#define BA      128       // atoms per block
#define WS_ELE  102400    // elements per repacked W matrix (10*2*10*64*8)

typedef __attribute__((ext_vector_type(8)))  short          short8v;
typedef __attribute__((ext_vector_type(16))) float          f32x16;

static __device__ __forceinline__ unsigned short f2bf(float f) {
  unsigned int u = __float_as_uint(f);
  u += 0x7fffu + ((u >> 16) & 1u);   // round-to-nearest-even
  return (unsigned short)(u >> 16);
}

static __device__ __forceinline__ short8v pack8(float4 a, float4 b) {
  short8v r;
  r[0] = (short)f2bf(a.x); r[1] = (short)f2bf(a.y);
  r[2] = (short)f2bf(a.z); r[3] = (short)f2bf(a.w);
  r[4] = (short)f2bf(b.x); r[5] = (short)f2bf(b.y);
  r[6] = (short)f2bf(b.z); r[7] = (short)f2bf(b.w);
  return r;
}

// Load 8 k-values (f32) starting at k0 from a row pointer, honoring the
// K=300 boundary (k0 is a multiple of 8; valid k < 300).
static __device__ __forceinline__ void loadA(const float* hp, int k0,
                                             float4& f0, float4& f1) {
  if (k0 <= 288) {
    f0 = *reinterpret_cast<const float4*>(hp + k0);
    f1 = *reinterpret_cast<const float4*>(hp + k0 + 4);
  } else if (k0 == 296) {
    f0 = *reinterpret_cast<const float4*>(hp + 296);   // k 296..299 valid
    f1 = make_float4(0.f, 0.f, 0.f, 0.f);
  } else {
    f0 = make_float4(0.f, 0.f, 0.f, 0.f);
    f1 = make_float4(0.f, 0.f, 0.f, 0.f);
  }
}

// async global->LDS, 16B per lane; lds base must be wave-uniform.
static __device__ __forceinline__ void stage16(const char* gsrc, char* ldst, int ln) {
  __builtin_amdgcn_global_load_lds(
      (const __attribute__((address_space(1))) void*)(gsrc + ln * 16),
      (__attribute__((address_space(3))) void*)ldst, 16, 0, 0);
}

// ---------------------------------------------------------------------------
// Prep: repack W1/V1 into B-fragment order [kc:10][ks:2][nt:10][lane:64][j:8],
// pad biases/readout vectors to 320, zero the segment-sum accumulators.
// ---------------------------------------------------------------------------
__global__ void prep_kernel(
    const float* __restrict__ W1, const float* __restrict__ V1,
    const float* __restrict__ b1, const float* __restrict__ vb1,
    const float* __restrict__ W2, const float* __restrict__ V2,
    unsigned short* __restrict__ W1s, unsigned short* __restrict__ V1s,
    float* __restrict__ b1p, float* __restrict__ vb1p,
    float* __restrict__ W2p, float* __restrict__ V2p,
    float* __restrict__ sums)
{
  const int t = blockIdx.x * 256 + threadIdx.x;
  if (t < 2 * WS_ELE) {
    const float* src = (t < WS_ELE) ? W1 : V1;
    unsigned short* dst = (t < WS_ELE) ? W1s : V1s;
    const int i    = (t < WS_ELE) ? t : t - WS_ELE;
    const int j    = i & 7;
    const int lane = (i >> 3) & 63;
    const int nt   = (i >> 9) % 10;
    const int ks   = (i / 5120) & 1;
    const int kc   = i / 10240;
    const int k = kc * 32 + ks * 16 + (lane >> 5) * 8 + j;
    const int n = nt * 32 + (lane & 31);
    const float v = (k < HID && n < HID) ? src[k * HID + n] : 0.f;
    dst[i] = f2bf(v);
  } else if (t < 2 * WS_ELE + 1280) {
    const int i = t - 2 * WS_ELE;
    const int which = i / 320;
    const int e = i - which * 320;
    const float* s = (which == 0) ? b1 : (which == 1) ? vb1 : (which == 2) ? W2 : V2;
    float*       d = (which == 0) ? b1p : (which == 1) ? vb1p : (which == 2) ? W2p : V2p;
    d[e] = (e < HID) ? s[e] : 0.f;
  } else if (t < 2 * WS_ELE + 1280 + 2 * N_MOLS) {
    sums[t - (2 * WS_ELE + 1280)] = 0.f;
  }
}

// ---------------------------------------------------------------------------
// Fused FFN x2 (W-pass and V-pass in ONE K-loop sharing A-fragments).
// Block = 128 atoms, 8 waves = 4 row-groups x 2 col-halves.
// A: global->reg f32->bf16 with next-chunk prefetch (no LDS for H).
// B: double-buffered 2x40KB LDS, staged via global_load_lds dwordx4.
// One barrier per 32-k chunk. Epilogue fuses relu->dot(W2)->row-reduce.
// ---------------------------------------------------------------------------
__global__ __launch_bounds__(512, 2) void fused_ffn(
    const float* __restrict__ hidden,
    const unsigned short* __restrict__ W1s, const unsigned short* __restrict__ V1s,
    const float* __restrict__ b1p, const float* __restrict__ vb1p,
    const float* __restrict__ W2p, const float* __restrict__ V2p,
    const float* __restrict__ b2, const float* __restrict__ vb2,
    float* __restrict__ outA, float* __restrict__ outW)
{
  // [buf:2][which:2][ks:2][nt:10][lane:64][j:8] bf16 = 81920 B
  __shared__ char bsB[2 * 40960];
  __shared__ float sOutA[BA];
  __shared__ float sOutW[BA];

  const int tid = (int)threadIdx.x;
  const int ln  = tid & 63;
  const int wv  = tid >> 6;
  const int wm  = wv >> 1;      // row group (0..3), 32 atoms each
  const int wn  = wv & 1;       // col half (0..1), 160 cols each
  const int l31 = ln & 31;
  const int lh  = ln >> 5;
  const long base = (long)blockIdx.x * BA;

  long rowl = base + wm * 32 + l31;
  if (rowl > N_ATOMS - 1) rowl = N_ATOMS - 1;   // clamp; results unused
  const float* hp = hidden + rowl * HID;

  const float bias2A = b2[0];
  const float bias2W = vb2[0];

  f32x16 accW[5] = {};
  f32x16 accV[5] = {};

  // ---- prologue: stage B chunk 0 into buf 0; load A chunk 0 ----
  {
    const char* wsrc = (const char*)W1s;   // kc=0
    const char* vsrc = (const char*)V1s;
    #pragma unroll
    for (int r = 0; r < 5; ++r) {
      const int c = r * 8 + wv;            // 40 x 1KB chunks
      const char* src = (c < 20) ? (wsrc + c * 1024) : (vsrc + (c - 20) * 1024);
      stage16(src, bsB + c * 1024, ln);
    }
  }
  float4 a0c, a1c, a2c, a3c;
  loadA(hp, lh * 8,      a0c, a1c);
  loadA(hp, 16 + lh * 8, a2c, a3c);
  __syncthreads();   // drains vmcnt: buf0 + A ready

  // ---- main loop over 10 K-chunks of 32 ----
  for (int kc = 0; kc < 10; ++kc) {
    const int cur = kc & 1;

    float4 a0n, a1n, a2n, a3n;
    if (kc < 9) {
      // issue next-chunk B staging (into other buffer) + next-chunk A loads
      const char* wsrc = (const char*)W1s + (kc + 1) * 20480;
      const char* vsrc = (const char*)V1s + (kc + 1) * 20480;
      char* dbase = bsB + (cur ^ 1) * 40960;
      #pragma unroll
      for (int r = 0; r < 5; ++r) {
        const int c = r * 8 + wv;
        const char* src = (c < 20) ? (wsrc + c * 1024) : (vsrc + (c - 20) * 1024);
        stage16(src, dbase + c * 1024, ln);
      }
      const int k0 = (kc + 1) * 32 + lh * 8;
      loadA(hp, k0,      a0n, a1n);
      loadA(hp, k0 + 16, a2n, a3n);
    }

    const short8v apk0 = pack8(a0c, a1c);   // ks = 0
    const short8v apk1 = pack8(a2c, a3c);   // ks = 1
    const char* bb = bsB + cur * 40960;

    #pragma unroll
    for (int nt = 0; nt < 5; ++nt) {
      const int ntg = wn * 5 + nt;
      const short8v bW0 = *reinterpret_cast<const short8v*>(bb + (0 * 10 + ntg) * 1024 + ln * 16);
      accW[nt] = __builtin_amdgcn_mfma_f32_32x32x16_bf16(apk0, bW0, accW[nt], 0, 0, 0);
      const short8v bW1 = *reinterpret_cast<const short8v*>(bb + (1 * 10 + ntg) * 1024 + ln * 16);
      accW[nt] = __builtin_amdgcn_mfma_f32_32x32x16_bf16(apk1, bW1, accW[nt], 0, 0, 0);
      const short8v bV0 = *reinterpret_cast<const short8v*>(bb + 20480 + (0 * 10 + ntg) * 1024 + ln * 16);
      accV[nt] = __builtin_amdgcn_mfma_f32_32x32x16_bf16(apk0, bV0, accV[nt], 0, 0, 0);
      const short8v bV1 = *reinterpret_cast<const short8v*>(bb + 20480 + (1 * 10 + ntg) * 1024 + ln * 16);
      accV[nt] = __builtin_amdgcn_mfma_f32_32x32x16_bf16(apk1, bV1, accV[nt], 0, 0, 0);
    }

    if (kc < 9) { a0c = a0n; a1c = a1n; a2c = a2n; a3c = a3n; }
    __syncthreads();   // next buffer staged; current buffer free for overwrite
  }

  // ---- epilogue: out[atom] = sum_n relu(X+b1)*W2 + b2, both passes ----
  float bvA[5], w2A[5], bvV[5], w2V[5];
  #pragma unroll
  for (int nt = 0; nt < 5; ++nt) {
    const int c = wn * 160 + nt * 32 + l31;
    bvA[nt] = b1p[c];  w2A[nt] = W2p[c];
    bvV[nt] = vb1p[c]; w2V[nt] = V2p[c];
  }
  if (tid < BA) { sOutA[tid] = 0.f; sOutW[tid] = 0.f; }
  __syncthreads();

  #pragma unroll
  for (int r = 0; r < 16; ++r) {
    float sA = 0.f, sW = 0.f;
    #pragma unroll
    for (int nt = 0; nt < 5; ++nt) {
      float xA = fmaxf(accW[nt][r] + bvA[nt], 0.f);
      sA = fmaf(xA, w2A[nt], sA);
      float xW = fmaxf(accV[nt][r] + bvV[nt], 0.f);
      sW = fmaf(xW, w2V[nt], sW);
    }
    sA += __shfl_xor(sA, 1);  sW += __shfl_xor(sW, 1);
    sA += __shfl_xor(sA, 2);  sW += __shfl_xor(sW, 2);
    sA += __shfl_xor(sA, 4);  sW += __shfl_xor(sW, 4);
    sA += __shfl_xor(sA, 8);  sW += __shfl_xor(sW, 8);
    sA += __shfl_xor(sA, 16); sW += __shfl_xor(sW, 16);
    if (l31 == 0) {
      const int row = (r & 3) + 8 * (r >> 2) + 4 * lh;
      atomicAdd(&sOutA[wm * 32 + row], sA);
      atomicAdd(&sOutW[wm * 32 + row], sW);
    }
  }
  __syncthreads();
  if (tid < BA) {
    const long atom = base + tid;
    if (atom < N_ATOMS) {
      outA[atom] = sOutA[tid] + bias2A;
      outW[atom] = sOutW[tid] + bias2W;
    }
  }
}

// ---------------------------------------------------------------------------
// Segment sums: sorted seg_ids, run-compress 8 atoms/thread before atomics.
// ---------------------------------------------------------------------------
__global__ void segsum_kernel(
    const float* __restrict__ outA, const float* __restrict__ outW,
    const int* __restrict__ seg,
    float* __restrict__ sum_o, float* __restrict__ sum_w)
{
  const long i0 = ((long)blockIdx.x * 256 + threadIdx.x) * 8;
  if (i0 >= N_ATOMS) return;
  const int4   s0 = *reinterpret_cast<const int4*>(seg + i0);
  const int4   s1 = *reinterpret_cast<const int4*>(seg + i0 + 4);
  const float4 o0 = *reinterpret_cast<const float4*>(outA + i0);
  const float4 o1 = *reinterpret_cast<const float4*>(outA + i0 + 4);
  const float4 w0 = *reinterpret_cast<const float4*>(outW + i0);
  const float4 w1 = *reinterpret_cast<const float4*>(outW + i0 + 4);
  const int   ss[8] = {s0.x, s0.y, s0.z, s0.w, s1.x, s1.y, s1.z, s1.w};
  const float oo[8] = {o0.x, o0.y, o0.z, o0.w, o1.x, o1.y, o1.z, o1.w};
  const float ww[8] = {w0.x, w0.y, w0.z, w0.w, w1.x, w1.y, w1.z, w1.w};
  int cur = ss[0];
  float ao = 0.f, aw = 0.f;
  #pragma unroll
  for (int j = 0; j < 8; ++j) {
    if (ss[j] != cur) {
      atomicAdd(&sum_o[cur], ao);
      atomicAdd(&sum_w[cur], aw);
      cur = ss[j]; ao = 0.f; aw = 0.f;
    }
    ao += oo[j]; aw += ww[j];
  }
  atomicAdd(&sum_o[cur], ao);
  atomicAdd(&sum_w[cur], aw);
}

// ---------------------------------------------------------------------------
// Final: out = output + weights * (0 - sum_o[seg]) / sum_w'[seg]
// ---------------------------------------------------------------------------
__global__ void final_kernel(
    const float* __restrict__ outA, const float* __restrict__ outW,
    const int* __restrict__ seg,
    const float* __restrict__ sum_o, const float* __restrict__ sum_w,
    float* __restrict__ out)
{
  const long i0 = ((long)blockIdx.x * 256 + threadIdx.x) * 4;
  if (i0 >= N_ATOMS) return;
  const int4   s4 = *reinterpret_cast<const int4*>(seg + i0);
  const float4 o4 = *reinterpret_cast<const float4*>(outA + i0);
  const float4 w4 = *reinterpret_cast<const float4*>(outW + i0);
  const int   ss[4] = {s4.x, s4.y, s4.z, s4.w};
  const float oo[4] = {o4.x, o4.y, o4.z, o4.w};
  const float ww[4] = {w4.x, w4.y, w4.z, w4.w};
  float r[4];
  #pragma unroll
  for (int j = 0; j < 4; ++j) {
    const int s = ss[j];
    float sw = sum_w[s];
    sw = (sw == 0.f) ? 1.f : sw;
    const float corr = (0.f - sum_o[s]) / sw;
    r[j] = oo[j] + ww[j] * corr;
  }
  *reinterpret_cast<float4*>(out + i0) = make_float4(r[0], r[1], r[2], r[3]);
}

// ---------------------------------------------------------------------------
extern "C" void kernel_launch(void* const* d_in, const int* in_sizes, int n_in,
                              void* d_out, int out_size, void* d_ws, size_t ws_size,
                              hipStream_t stream)
{
  const float* hidden = (const float*)d_in[0];
  const int*   seg    = (const int*)d_in[1];
  const float* W1     = (const float*)d_in[2];
  const float* b1     = (const float*)d_in[3];
  const float* W2     = (const float*)d_in[4];
  const float* b2     = (const float*)d_in[5];
  const float* V1     = (const float*)d_in[6];
  const float* vb1    = (const float*)d_in[7];
  const float* V2     = (const float*)d_in[8];
  const float* vb2    = (const float*)d_in[9];

  char* ws = (char*)d_ws;
  float*          outA  = (float*)(ws + 0);          // 2,000,000 B
  float*          outW  = (float*)(ws + 2000000);    // 2,000,000 B
  float*          sum_o = (float*)(ws + 4000000);    //   100,000 B
  float*          sum_w = (float*)(ws + 4100000);    //   100,000 B
  unsigned short* W1s   = (unsigned short*)(ws + 4200000);  // 204,800 B
  unsigned short* V1s   = (unsigned short*)(ws + 4404800);  // 204,800 B
  float*          b1p   = (float*)(ws + 4609600);    // 1,280 B
  float*          vb1p  = (float*)(ws + 4610880);
  float*          W2p   = (float*)(ws + 4612160);
  float*          V2p   = (float*)(ws + 4613440);

  prep_kernel<<<1001, 256, 0, stream>>>(W1, V1, b1, vb1, W2, V2,
                                        W1s, V1s, b1p, vb1p, W2p, V2p, sum_o);

  const int nblk = (N_ATOMS + BA - 1) / BA;   // 3907
  fused_ffn<<<nblk, 512, 0, stream>>>(hidden, W1s, V1s, b1p, vb1p, W2p, V2p,
                                      b2, vb2, outA, outW);

  segsum_kernel<<<(N_ATOMS / 8 + 255) / 256, 256, 0, stream>>>(outA, outW, seg,
                                                               sum_o, sum_w);

  final_kernel<<<(N_ATOMS / 4 + 255) / 256, 256, 0, stream>>>(outA, outW, seg,
                                                              sum_o, sum_w,
                                                              (float*)d_out);
}